// Round 1
// baseline (10079.741 us; speedup 1.0000x reference)
//
#include <hip/hip_runtime.h>

// LSTM LM: embed -> x@W (bf16 MFMA) -> 2048-step recurrence (persistent
// 64-WG kernel, weights in registers, flag dataflow sync) -> H@V bf16 MFMA
// -> fused log-softmax.
//
// ws layout (bytes), total ~78.8 MB:
//   XG    f32 [2048][2048]   @ 0          (16777216)
//   H     f32 [2048][512]    @ 16777216   (4194304)
//   Hb    bf16[2048][512]    @ 20971520   (2097152)
//   Xb    bf16[2048][512]    @ 23068672   (2097152)
//   Wt    bf16[2048][512]    @ 25165824   (2097152)  (W^T, gates f,i,c,o)
//   VT    bf16[50304][512]   @ 27262976   (51511296) (V^T, padded rows)
//   bcat  f32 [2048]         @ 78774272   (8192)
//   flags int [64]           @ 78782464

typedef unsigned short u16;
typedef __attribute__((ext_vector_type(8))) short bf16x8;
typedef __attribute__((ext_vector_type(4))) float f32x4;

#define SEQ_T 2048
#define DIM 512
#define NVOC 50257

__device__ inline u16 f2bf(float f) {
  union { float f; unsigned u; } v; v.f = f;
  unsigned u = v.u;
  u += 0x7fffu + ((u >> 16) & 1u);   // round-to-nearest-even
  return (u16)(u >> 16);
}

// ---------------- misc: zero flags, build concatenated bias ----------------
__global__ __launch_bounds__(256) void misc_kernel(int* flags, float* bcat,
    const float* bf_, const float* bi_, const float* bc_, const float* bo_) {
  int i = blockIdx.x * 256 + threadIdx.x;
  if (i < 64) flags[i] = 0;
  if (i < 2048) {
    const float* b = (i < 512) ? bf_ : (i < 1024) ? bi_ : (i < 1536) ? bc_ : bo_;
    bcat[i] = b[i & 511];
  }
}

// ---------------- embed: Xb[t][d] = bf16(emb[idx[t]][d]) ----------------
__global__ __launch_bounds__(128) void embed_kernel(const int* __restrict__ idx,
    const float* __restrict__ emb, u16* __restrict__ Xb) {
  int t = blockIdx.x;
  int row = idx[t];
  const float4* src = (const float4*)(emb + (size_t)row * DIM);
  float4 v = src[threadIdx.x];
  ushort4 o;
  o.x = f2bf(v.x); o.y = f2bf(v.y); o.z = f2bf(v.z); o.w = f2bf(v.w);
  *(ushort4*)(Xb + (size_t)t * DIM + threadIdx.x * 4) = o;
}

// ------- transpose+convert: dst[n][k] (bf16, row stride 512) = src[k][n] -------
__global__ __launch_bounds__(256) void transpose_kernel(const float* __restrict__ src,
    u16* __restrict__ dst, int Nsrc, int Nvalid) {
  __shared__ float tile[32][33];
  int n0 = blockIdx.x * 32, k0 = blockIdx.y * 32;
  int tx = threadIdx.x & 31, ty = threadIdx.x >> 5;   // 32 x 8
#pragma unroll
  for (int r = 0; r < 32; r += 8) {
    int n = n0 + tx;
    float v = 0.f;
    if (n < Nvalid) v = src[(size_t)(k0 + ty + r) * Nsrc + n];
    tile[ty + r][tx] = v;
  }
  __syncthreads();
#pragma unroll
  for (int r = 0; r < 32; r += 8) {
    int n = n0 + ty + r;
    if (n < Nvalid) dst[(size_t)n * DIM + k0 + tx] = f2bf(tile[tx][ty + r]);
  }
}

// ---------------- bf16 MFMA GEMM: C[M][N] = A[M][K] * Bt[N][K]^T + bias ----------------
// BM=BN=128, BK=32, 256 threads (4 waves in 2x2), 4x4 16x16x32 MFMA tiles/wave.
// LDS row stride 40 shorts (pad 32->40) keeps ds_read_b128 at 2-way (free).
__global__ __launch_bounds__(256) void gemm_bt(const u16* __restrict__ A,
    const u16* __restrict__ Bt, float* __restrict__ C, const float* __restrict__ bias,
    int M, int Nvalid, int K, long ldc) {
  __shared__ u16 As[128 * 40];
  __shared__ u16 Bs[128 * 40];
  int n0 = blockIdx.x * 128, m0 = blockIdx.y * 128;
  int tid = threadIdx.x;
  int wave = tid >> 6, lane = tid & 63;
  int wm = (wave >> 1) * 64, wn = (wave & 1) * 64;
  int qm = lane & 15, quad = lane >> 4;
  f32x4 acc[4][4] = {};

  for (int kt = 0; kt < K; kt += 32) {
#pragma unroll
    for (int i = 0; i < 2; ++i) {
      int c = tid + i * 256;
      int row = c >> 2, kc = (c & 3) << 3;
      uint4 va = *(const uint4*)(A + (size_t)(m0 + row) * K + kt + kc);
      *(uint4*)(&As[row * 40 + kc]) = va;
      int nrow = n0 + row;
      uint4 vb = make_uint4(0u, 0u, 0u, 0u);
      if (nrow < Nvalid) vb = *(const uint4*)(Bt + (size_t)nrow * K + kt + kc);
      *(uint4*)(&Bs[row * 40 + kc]) = vb;
    }
    __syncthreads();
    bf16x8 a[4], b[4];
#pragma unroll
    for (int mt = 0; mt < 4; ++mt)
      a[mt] = *(const bf16x8*)(&As[(wm + mt * 16 + qm) * 40 + quad * 8]);
#pragma unroll
    for (int nt = 0; nt < 4; ++nt)
      b[nt] = *(const bf16x8*)(&Bs[(wn + nt * 16 + qm) * 40 + quad * 8]);
#pragma unroll
    for (int mt = 0; mt < 4; ++mt)
#pragma unroll
      for (int nt = 0; nt < 4; ++nt)
        acc[mt][nt] = __builtin_amdgcn_mfma_f32_16x16x32_bf16(a[mt], b[nt], acc[mt][nt], 0, 0, 0);
    __syncthreads();
  }
#pragma unroll
  for (int mt = 0; mt < 4; ++mt)
#pragma unroll
    for (int nt = 0; nt < 4; ++nt) {
      int n = n0 + wn + nt * 16 + qm;
      if (n >= Nvalid) continue;
      float bv = bias[n];
#pragma unroll
      for (int r = 0; r < 4; ++r) {
        int m = m0 + wm + mt * 16 + quad * 4 + r;
        C[(size_t)m * ldc + n] = acc[mt][nt][r] + bv;
      }
    }
}

// ---------------- recurrence: 64 persistent WGs, weights in registers ----------------
// WG w owns h columns [8w, 8w+8). wave = gate (0=f,1=i,2=c~,3=o).
// Lane: grp = lane>>5 (4-col half), s = lane&31 (16 rows, stride 32).
// Sync: producer release-stores flags[w]=t+1; consumers poll all 64 flags
// (one coalesced wave load + __all). h traffic is agent-scope (sc1) to dodge
// per-XCD L2 non-coherence without any cache-invalidate fences in the loop.
__global__ __launch_bounds__(256) void lstm_kernel(const float* __restrict__ XG,
    const float* __restrict__ Uf, const float* __restrict__ Ui,
    const float* __restrict__ Uc, const float* __restrict__ Uo,
    float* __restrict__ H, u16* __restrict__ Hb, int* __restrict__ flags) {
  int w = blockIdx.x;
  int tid = threadIdx.x;
  int wave = tid >> 6;
  int lane = tid & 63;
  int grp = lane >> 5, s = lane & 31;
  const float* U = (wave == 0) ? Uf : (wave == 1) ? Ui : (wave == 2) ? Uc : Uo;
  int colbase = w * 8 + grp * 4;

  float wt[16][4];
#pragma unroll
  for (int j = 0; j < 16; ++j) {
    int row = s + 32 * j;
#pragma unroll
    for (int m = 0; m < 4; ++m) wt[j][m] = U[(size_t)row * DIM + colbase + m];
  }

  __shared__ float gact[4][8];
  float c_reg = 0.f;

  for (int t = 0; t < SEQ_T; ++t) {
    float pre;
    if (t > 0) {
      if (tid < 64) {   // wave 0 polls all 64 flags: coalesced load + __all
        int fv;
        do {
          fv = __hip_atomic_load(flags + lane, __ATOMIC_RELAXED, __HIP_MEMORY_SCOPE_AGENT);
        } while (!__all(fv >= t));
      }
      __syncthreads();
      const float* hrow = H + (size_t)(t - 1) * DIM;
      float hreg[16];
#pragma unroll
      for (int j = 0; j < 16; ++j)
        hreg[j] = __hip_atomic_load(hrow + s + 32 * j, __ATOMIC_RELAXED, __HIP_MEMORY_SCOPE_AGENT);
      float acc0 = 0.f, acc1 = 0.f, acc2 = 0.f, acc3 = 0.f;
#pragma unroll
      for (int j = 0; j < 16; ++j) {
        acc0 += hreg[j] * wt[j][0];
        acc1 += hreg[j] * wt[j][1];
        acc2 += hreg[j] * wt[j][2];
        acc3 += hreg[j] * wt[j][3];
      }
#pragma unroll
      for (int off = 1; off < 32; off <<= 1) {
        acc0 += __shfl_xor(acc0, off, 64);
        acc1 += __shfl_xor(acc1, off, 64);
        acc2 += __shfl_xor(acc2, off, 64);
        acc3 += __shfl_xor(acc3, off, 64);
      }
      if (s < 4) {
        float a = (s == 0) ? acc0 : (s == 1) ? acc1 : (s == 2) ? acc2 : acc3;
        pre = a + XG[(size_t)t * 2048 + wave * 512 + colbase + s];
      }
    } else {
      if (s < 4) pre = XG[wave * 512 + colbase + s];
    }
    if (s < 4)
      gact[wave][grp * 4 + s] = (wave == 2) ? tanhf(pre) : 1.f / (1.f + __expf(-pre));
    __syncthreads();
    if (tid < 8) {
      float f = gact[0][tid], i = gact[1][tid], ct = gact[2][tid], o = gact[3][tid];
      c_reg = f * c_reg + i * ct;
      float h = o * tanhf(c_reg);
      __hip_atomic_store(H + (size_t)t * DIM + w * 8 + tid, h,
                         __ATOMIC_RELAXED, __HIP_MEMORY_SCOPE_AGENT);
      Hb[(size_t)t * DIM + w * 8 + tid] = f2bf(h);
    }
    if (tid == 0)   // release orders wave 0's h stores before the flag
      __hip_atomic_store(flags + w, t + 1, __ATOMIC_RELEASE, __HIP_MEMORY_SCOPE_AGENT);
    // next iteration's leading __syncthreads covers the gact WAR hazard
  }
}

// ---------------- fused per-row log-softmax (in place on d_out) ----------------
__global__ __launch_bounds__(256) void softmax_kernel(float* __restrict__ out) {
  float* row = out + (size_t)blockIdx.x * NVOC;
  int tid = threadIdx.x;
  float m = -1e30f, ssum = 0.f;
  for (int i = tid; i < NVOC; i += 256) {
    float x = row[i];
    if (x > m) { ssum = ssum * __expf(m - x) + 1.f; m = x; }
    else ssum += __expf(x - m);
  }
#pragma unroll
  for (int off = 1; off < 64; off <<= 1) {
    float m2 = __shfl_xor(m, off, 64);
    float s2 = __shfl_xor(ssum, off, 64);
    float mn = fmaxf(m, m2);
    ssum = ssum * __expf(m - mn) + s2 * __expf(m2 - mn);
    m = mn;
  }
  __shared__ float sm[4], ss[4];
  int wv = tid >> 6, lane = tid & 63;
  if (lane == 0) { sm[wv] = m; ss[wv] = ssum; }
  __syncthreads();
  if (tid == 0) {
    float M = sm[0], S = ss[0];
#pragma unroll
    for (int k = 1; k < 4; ++k) {
      float mn = fmaxf(M, sm[k]);
      S = S * __expf(M - mn) + ss[k] * __expf(sm[k] - mn);
      M = mn;
    }
    sm[0] = M + __logf(S);
  }
  __syncthreads();
  float lse = sm[0];
  for (int i = tid; i < NVOC; i += 256) row[i] -= lse;
}

extern "C" void kernel_launch(void* const* d_in, const int* in_sizes, int n_in,
                              void* d_out, int out_size, void* d_ws, size_t ws_size,
                              hipStream_t stream) {
  const int*   idx = (const int*)d_in[0];
  const float* emb = (const float*)d_in[1];
  const float* Wf  = (const float*)d_in[2];
  const float* Wi  = (const float*)d_in[3];
  const float* Wc  = (const float*)d_in[4];
  const float* Wo  = (const float*)d_in[5];
  const float* Uf  = (const float*)d_in[6];
  const float* Ui  = (const float*)d_in[7];
  const float* Uc  = (const float*)d_in[8];
  const float* Uo  = (const float*)d_in[9];
  const float* bf_ = (const float*)d_in[10];
  const float* bi_ = (const float*)d_in[11];
  const float* bc_ = (const float*)d_in[12];
  const float* bo_ = (const float*)d_in[13];
  const float* V   = (const float*)d_in[14];
  const float* by  = (const float*)d_in[15];
  float* out = (float*)d_out;
  char* ws = (char*)d_ws;

  float* XG   = (float*)(ws + 0);
  float* H    = (float*)(ws + 16777216);
  u16*   Hb   = (u16*)  (ws + 20971520);
  u16*   Xb   = (u16*)  (ws + 23068672);
  u16*   Wt   = (u16*)  (ws + 25165824);
  u16*   VT   = (u16*)  (ws + 27262976);
  float* bcat = (float*)(ws + 78774272);
  int*   flags= (int*)  (ws + 78782464);

  misc_kernel<<<8, 256, 0, stream>>>(flags, bcat, bf_, bi_, bc_, bo_);
  embed_kernel<<<SEQ_T, 128, 0, stream>>>(idx, emb, Xb);
  const float* Ws[4] = {Wf, Wi, Wc, Wo};
  for (int g = 0; g < 4; ++g)
    transpose_kernel<<<dim3(16, 16), 256, 0, stream>>>(Ws[g], Wt + (size_t)g * 512 * 512, 512, 512);
  transpose_kernel<<<dim3(1571, 16), 256, 0, stream>>>(V, VT, NVOC, NVOC);
  // XG[t][g*512+c] = x @ W_g + b_g
  gemm_bt<<<dim3(16, 16), 256, 0, stream>>>(Xb, Wt, XG, bcat, SEQ_T, 2048, DIM, 2048);
  lstm_kernel<<<64, 256, 0, stream>>>(XG, Uf, Ui, Uc, Uo, H, Hb, flags);
  // logits = H @ V + by  -> d_out
  gemm_bt<<<dim3(393, 16), 256, 0, stream>>>(Hb, VT, out, by, SEQ_T, NVOC, DIM, NVOC);
  softmax_kernel<<<SEQ_T, 256, 0, stream>>>(out);
}

// Round 2
// 5686.354 us; speedup vs baseline: 1.7726x; 1.7726x over previous
//
#include <hip/hip_runtime.h>

// LSTM LM: embed -> x@W (bf16 MFMA) -> 2048-step recurrence (persistent
// 64-WG kernel, weights in registers, TAGGED-DATA dataflow sync: one word
// per h element = (bf16(h)<<16)|(t+1), so flag==data, 1 remote RTT/step)
// -> H@V bf16 MFMA -> fused log-softmax.
//
// ws layout (bytes), total ~78.8 MB:
//   XG    f32 [2048][2048]   @ 0          (16777216)
//   Hp    u32 [2048][512]    @ 16777216   (4194304)  packed bf16 h | tag
//   Hb    bf16[2048][512]    @ 20971520   (2097152)
//   Xb    bf16[2048][512]    @ 23068672   (2097152)
//   Wt    bf16[2048][512]    @ 25165824   (2097152)  (W^T, gates f,i,c,o)
//   VT    bf16[50304][512]   @ 27262976   (51511296) (V^T, padded rows)
//   bcat  f32 [2048]         @ 78774272   (8192)

typedef unsigned short u16;
typedef unsigned int u32;
typedef __attribute__((ext_vector_type(8))) short bf16x8;
typedef __attribute__((ext_vector_type(4))) float f32x4;

#define SEQ_T 2048
#define DIM 512
#define NVOC 50257

__device__ inline u16 f2bf(float f) {
  union { float f; unsigned u; } v; v.f = f;
  unsigned u = v.u;
  u += 0x7fffu + ((u >> 16) & 1u);   // round-to-nearest-even
  return (u16)(u >> 16);
}

// ---------------- misc: build concatenated bias ----------------
__global__ __launch_bounds__(256) void misc_kernel(float* bcat,
    const float* bf_, const float* bi_, const float* bc_, const float* bo_) {
  int i = blockIdx.x * 256 + threadIdx.x;
  if (i < 2048) {
    const float* b = (i < 512) ? bf_ : (i < 1024) ? bi_ : (i < 1536) ? bc_ : bo_;
    bcat[i] = b[i & 511];
  }
}

// ---------------- embed: Xb[t][d] = bf16(emb[idx[t]][d]) ----------------
__global__ __launch_bounds__(128) void embed_kernel(const int* __restrict__ idx,
    const float* __restrict__ emb, u16* __restrict__ Xb) {
  int t = blockIdx.x;
  int row = idx[t];
  const float4* src = (const float4*)(emb + (size_t)row * DIM);
  float4 v = src[threadIdx.x];
  ushort4 o;
  o.x = f2bf(v.x); o.y = f2bf(v.y); o.z = f2bf(v.z); o.w = f2bf(v.w);
  *(ushort4*)(Xb + (size_t)t * DIM + threadIdx.x * 4) = o;
}

// ------- transpose+convert: dst[n][k] (bf16, row stride 512) = src[k][n] -------
__global__ __launch_bounds__(256) void transpose_kernel(const float* __restrict__ src,
    u16* __restrict__ dst, int Nsrc, int Nvalid) {
  __shared__ float tile[32][33];
  int n0 = blockIdx.x * 32, k0 = blockIdx.y * 32;
  int tx = threadIdx.x & 31, ty = threadIdx.x >> 5;   // 32 x 8
#pragma unroll
  for (int r = 0; r < 32; r += 8) {
    int n = n0 + tx;
    float v = 0.f;
    if (n < Nvalid) v = src[(size_t)(k0 + ty + r) * Nsrc + n];
    tile[ty + r][tx] = v;
  }
  __syncthreads();
#pragma unroll
  for (int r = 0; r < 32; r += 8) {
    int n = n0 + ty + r;
    if (n < Nvalid) dst[(size_t)n * DIM + k0 + tx] = f2bf(tile[tx][ty + r]);
  }
}

// ---------------- bf16 MFMA GEMM: C[M][N] = A[M][K] * Bt[N][K]^T + bias ----------------
__global__ __launch_bounds__(256) void gemm_bt(const u16* __restrict__ A,
    const u16* __restrict__ Bt, float* __restrict__ C, const float* __restrict__ bias,
    int M, int Nvalid, int K, long ldc) {
  __shared__ u16 As[128 * 40];
  __shared__ u16 Bs[128 * 40];
  int n0 = blockIdx.x * 128, m0 = blockIdx.y * 128;
  int tid = threadIdx.x;
  int wave = tid >> 6, lane = tid & 63;
  int wm = (wave >> 1) * 64, wn = (wave & 1) * 64;
  int qm = lane & 15, quad = lane >> 4;
  f32x4 acc[4][4] = {};

  for (int kt = 0; kt < K; kt += 32) {
#pragma unroll
    for (int i = 0; i < 2; ++i) {
      int c = tid + i * 256;
      int row = c >> 2, kc = (c & 3) << 3;
      uint4 va = *(const uint4*)(A + (size_t)(m0 + row) * K + kt + kc);
      *(uint4*)(&As[row * 40 + kc]) = va;
      int nrow = n0 + row;
      uint4 vb = make_uint4(0u, 0u, 0u, 0u);
      if (nrow < Nvalid) vb = *(const uint4*)(Bt + (size_t)nrow * K + kt + kc);
      *(uint4*)(&Bs[row * 40 + kc]) = vb;
    }
    __syncthreads();
    bf16x8 a[4], b[4];
#pragma unroll
    for (int mt = 0; mt < 4; ++mt)
      a[mt] = *(const bf16x8*)(&As[(wm + mt * 16 + qm) * 40 + quad * 8]);
#pragma unroll
    for (int nt = 0; nt < 4; ++nt)
      b[nt] = *(const bf16x8*)(&Bs[(wn + nt * 16 + qm) * 40 + quad * 8]);
#pragma unroll
    for (int mt = 0; mt < 4; ++mt)
#pragma unroll
      for (int nt = 0; nt < 4; ++nt)
        acc[mt][nt] = __builtin_amdgcn_mfma_f32_16x16x32_bf16(a[mt], b[nt], acc[mt][nt], 0, 0, 0);
    __syncthreads();
  }
#pragma unroll
  for (int mt = 0; mt < 4; ++mt)
#pragma unroll
    for (int nt = 0; nt < 4; ++nt) {
      int n = n0 + wn + nt * 16 + qm;
      if (n >= Nvalid) continue;
      float bv = bias[n];
#pragma unroll
      for (int r = 0; r < 4; ++r) {
        int m = m0 + wm + mt * 16 + quad * 4 + r;
        C[(size_t)m * ldc + n] = acc[mt][nt][r] + bv;
      }
    }
}

// ---------------- recurrence: 64 persistent WGs, weights in registers ----------------
// WG w owns h columns [8w, 8w+8). wave = gate (0=f,1=i,2=c~,3=o).
// Sync: h element for step t is stored as (bf16(h)<<16)|(t+1) — data and flag
// in one word, so a matching tag implies valid data: one remote RTT per step,
// no fences. Poison 0xAAAAAAAA has tag 0xAAAA, never matches t+1 <= 2048.
// XG row is prefetched before the poll (h-independent, hides its HBM latency).
__global__ __launch_bounds__(256) void lstm_kernel(const float* __restrict__ XG,
    const float* __restrict__ Uf, const float* __restrict__ Ui,
    const float* __restrict__ Uc, const float* __restrict__ Uo,
    u32* __restrict__ Hp, u16* __restrict__ Hb) {
  int w = blockIdx.x;
  int tid = threadIdx.x;
  int wave = tid >> 6;
  int lane = tid & 63;
  int grp = lane >> 5, s = lane & 31;
  const float* U = (wave == 0) ? Uf : (wave == 1) ? Ui : (wave == 2) ? Uc : Uo;
  int colbase = w * 8 + grp * 4;

  float wt[16][4];
#pragma unroll
  for (int j = 0; j < 16; ++j) {
    int row = s + 32 * j;
#pragma unroll
    for (int m = 0; m < 4; ++m) wt[j][m] = U[(size_t)row * DIM + colbase + m];
  }

  __shared__ float gact[2][4][8];   // double-buffered by t&1 -> one barrier/step
  float c_reg = 0.f;

  for (int t = 0; t < SEQ_T; ++t) {
    // prefetch XG (independent of h) so its latency overlaps the poll
    float xg = 0.f;
    if (s < 4) xg = XG[(size_t)t * 2048 + wave * 512 + colbase + s];

    float acc0 = 0.f, acc1 = 0.f, acc2 = 0.f, acc3 = 0.f;
    if (t > 0) {
      const u32* hrow = Hp + (size_t)(t - 1) * DIM;   // tagged with t
      u32 hp[16];
      bool ok;
      do {
#pragma unroll
        for (int j = 0; j < 16; ++j)
          hp[j] = __hip_atomic_load(hrow + s + 32 * j, __ATOMIC_RELAXED,
                                    __HIP_MEMORY_SCOPE_AGENT);
        ok = true;
#pragma unroll
        for (int j = 0; j < 16; ++j) ok &= ((hp[j] & 0xffffu) == (u32)t);
      } while (!__all(ok));
#pragma unroll
      for (int j = 0; j < 16; ++j) {
        union { u32 u; float f; } cv; cv.u = hp[j] & 0xffff0000u;
        float hv = cv.f;
        acc0 += hv * wt[j][0];
        acc1 += hv * wt[j][1];
        acc2 += hv * wt[j][2];
        acc3 += hv * wt[j][3];
      }
#pragma unroll
      for (int off = 1; off < 32; off <<= 1) {
        acc0 += __shfl_xor(acc0, off, 64);
        acc1 += __shfl_xor(acc1, off, 64);
        acc2 += __shfl_xor(acc2, off, 64);
        acc3 += __shfl_xor(acc3, off, 64);
      }
    }
    if (s < 4) {
      float a = (s == 0) ? acc0 : (s == 1) ? acc1 : (s == 2) ? acc2 : acc3;
      float pre = a + xg;
      gact[t & 1][wave][grp * 4 + s] = (wave == 2) ? tanhf(pre)
                                                   : 1.f / (1.f + __expf(-pre));
    }
    __syncthreads();
    if (tid < 8) {
      float f = gact[t & 1][0][tid], i = gact[t & 1][1][tid];
      float ct = gact[t & 1][2][tid], o = gact[t & 1][3][tid];
      c_reg = f * c_reg + i * ct;
      float h = o * tanhf(c_reg);
      u16 hb = f2bf(h);
      Hb[(size_t)t * DIM + w * 8 + tid] = hb;
      __hip_atomic_store(Hp + (size_t)t * DIM + w * 8 + tid,
                         ((u32)hb << 16) | (u32)(t + 1),
                         __ATOMIC_RELAXED, __HIP_MEMORY_SCOPE_AGENT);
    }
    // WAR on gact[t&1] (rewritten at t+2) is ordered by step t+1's barrier:
    // no wave reaches t+2 writes until wave0 (which read at t) passes t+1.
  }
}

// ---------------- fused per-row log-softmax (in place on d_out) ----------------
__global__ __launch_bounds__(256) void softmax_kernel(float* __restrict__ out) {
  float* row = out + (size_t)blockIdx.x * NVOC;
  int tid = threadIdx.x;
  float m = -1e30f, ssum = 0.f;
  for (int i = tid; i < NVOC; i += 256) {
    float x = row[i];
    if (x > m) { ssum = ssum * __expf(m - x) + 1.f; m = x; }
    else ssum += __expf(x - m);
  }
#pragma unroll
  for (int off = 1; off < 64; off <<= 1) {
    float m2 = __shfl_xor(m, off, 64);
    float s2 = __shfl_xor(ssum, off, 64);
    float mn = fmaxf(m, m2);
    ssum = ssum * __expf(m - mn) + s2 * __expf(m2 - mn);
    m = mn;
  }
  __shared__ float sm[4], ss[4];
  int wv = tid >> 6, lane = tid & 63;
  if (lane == 0) { sm[wv] = m; ss[wv] = ssum; }
  __syncthreads();
  if (tid == 0) {
    float M = sm[0], S = ss[0];
#pragma unroll
    for (int k = 1; k < 4; ++k) {
      float mn = fmaxf(M, sm[k]);
      S = S * __expf(M - mn) + ss[k] * __expf(sm[k] - mn);
      M = mn;
    }
    sm[0] = M + __logf(S);
  }
  __syncthreads();
  float lse = sm[0];
  for (int i = tid; i < NVOC; i += 256) row[i] -= lse;
}

extern "C" void kernel_launch(void* const* d_in, const int* in_sizes, int n_in,
                              void* d_out, int out_size, void* d_ws, size_t ws_size,
                              hipStream_t stream) {
  const int*   idx = (const int*)d_in[0];
  const float* emb = (const float*)d_in[1];
  const float* Wf  = (const float*)d_in[2];
  const float* Wi  = (const float*)d_in[3];
  const float* Wc  = (const float*)d_in[4];
  const float* Wo  = (const float*)d_in[5];
  const float* Uf  = (const float*)d_in[6];
  const float* Ui  = (const float*)d_in[7];
  const float* Uc  = (const float*)d_in[8];
  const float* Uo  = (const float*)d_in[9];
  const float* bf_ = (const float*)d_in[10];
  const float* bi_ = (const float*)d_in[11];
  const float* bc_ = (const float*)d_in[12];
  const float* bo_ = (const float*)d_in[13];
  const float* V   = (const float*)d_in[14];
  const float* by  = (const float*)d_in[15];
  float* out = (float*)d_out;
  char* ws = (char*)d_ws;

  float* XG   = (float*)(ws + 0);
  u32*   Hp   = (u32*)  (ws + 16777216);
  u16*   Hb   = (u16*)  (ws + 20971520);
  u16*   Xb   = (u16*)  (ws + 23068672);
  u16*   Wt   = (u16*)  (ws + 25165824);
  u16*   VT   = (u16*)  (ws + 27262976);
  float* bcat = (float*)(ws + 78774272);

  misc_kernel<<<8, 256, 0, stream>>>(bcat, bf_, bi_, bc_, bo_);
  embed_kernel<<<SEQ_T, 128, 0, stream>>>(idx, emb, Xb);
  const float* Ws[4] = {Wf, Wi, Wc, Wo};
  for (int g = 0; g < 4; ++g)
    transpose_kernel<<<dim3(16, 16), 256, 0, stream>>>(Ws[g], Wt + (size_t)g * 512 * 512, 512, 512);
  transpose_kernel<<<dim3(1571, 16), 256, 0, stream>>>(V, VT, NVOC, NVOC);
  // XG[t][g*512+c] = x @ W_g + b_g
  gemm_bt<<<dim3(16, 16), 256, 0, stream>>>(Xb, Wt, XG, bcat, SEQ_T, 2048, DIM, 2048);
  lstm_kernel<<<64, 256, 0, stream>>>(XG, Uf, Ui, Uc, Uo, Hp, Hb);
  // logits = H @ V + by  -> d_out
  gemm_bt<<<dim3(393, 16), 256, 0, stream>>>(Hb, VT, out, by, SEQ_T, NVOC, DIM, NVOC);
  softmax_kernel<<<SEQ_T, 256, 0, stream>>>(out);
}